// Round 11
// baseline (171.405 us; speedup 1.0000x reference)
//
#include <hip/hip_runtime.h>
#include <math.h>

#define C_C   0.01f
#define SQC   0.1f          // sqrt(c)
#define EPSF  1e-15f
#define TCLIP (1.0f - 1e-6f)

typedef short short8 __attribute__((ext_vector_type(8)));
typedef float f32x4  __attribute__((ext_vector_type(4)));

__device__ __forceinline__ float wred(float v) {
#pragma unroll
    for (int off = 32; off > 0; off >>= 1) v += __shfl_xor(v, off, 64);
    return v;
}

__device__ __forceinline__ float dot4(const float4& a, const float4& b) {
    return a.x * b.x + a.y * b.y + a.z * b.z + a.w * b.w;
}

// fp32 -> bf16 round-nearest-even, raw bits
__device__ __forceinline__ unsigned int f2bf(float f) {
    unsigned int u = __float_as_uint(f);
    u += 0x7fffu + ((u >> 16) & 1u);
    return u >> 16;
}
__device__ __forceinline__ unsigned int pk2(float a, float b) {
    return f2bf(a) | (f2bf(b) << 16);
}

// ---------------------------------------------------------------------------
// Kernel 1: build 128 queries; emit bf16 rows + fp32 q2 + subject bias.
// One wave per query.
// ---------------------------------------------------------------------------
__global__ __launch_bounds__(64)
void build_queries(const float* __restrict__ ent,
                   const float* __restrict__ rrot,
                   const float* __restrict__ rtrans,
                   const float* __restrict__ ebias,
                   const int* __restrict__ trip,
                   unsigned short* __restrict__ qb,  // [B][512] bf16 bits
                   float* __restrict__ q2buf,        // [B]
                   float* __restrict__ sbbuf)        // [B]
{
    const int b    = blockIdx.x;
    const int lane = threadIdx.x;
    const int t0   = trip[b * 3 + 0];
    const int r    = trip[b * 3 + 1];

    const float* srow = ent + (size_t)t0 * 512;
    float4 s0 = *(const float4*)(srow + 4 * lane);
    float4 s1 = *(const float4*)(srow + 256 + 4 * lane);

    // log_map_zero
    float ss = dot4(s0, s0) + dot4(s1, s1);
    ss = wred(ss);
    float yn  = fmaxf(sqrtf(ss), EPSF);
    float arg = fminf(SQC * yn, TCLIP);
    float fl  = atanhf(arg) / (SQC * yn);

    // givens rotation on s_tan = fl * s
    const float* arow = rrot + (size_t)r * 256;
    float2 a01 = *(const float2*)(arow + 2 * lane);
    float2 a23 = *(const float2*)(arow + 128 + 2 * lane);
    float c0, n0, c1, n1, c2, n2, c3, n3;
    sincosf(a01.x, &n0, &c0);
    sincosf(a01.y, &n1, &c1);
    sincosf(a23.x, &n2, &c2);
    sincosf(a23.y, &n3, &c3);

    float t0x = s0.x * fl, t0y = s0.y * fl, t0z = s0.z * fl, t0w = s0.w * fl;
    float t1x = s1.x * fl, t1y = s1.y * fl, t1z = s1.z * fl, t1w = s1.w * fl;

    float4 r0, r1;
    r0.x = c0 * t0x - n0 * t0y;  r0.y = n0 * t0x + c0 * t0y;
    r0.z = c1 * t0z - n1 * t0w;  r0.w = n1 * t0z + c1 * t0w;
    r1.x = c2 * t1x - n2 * t1y;  r1.y = n2 * t1x + c2 * t1y;
    r1.z = c3 * t1z - n3 * t1w;  r1.w = n3 * t1z + c3 * t1w;

    // exp_map_zero(rot)
    float vv = dot4(r0, r0) + dot4(r1, r1);
    vv = wred(vv);
    float vn = fmaxf(sqrtf(vv), EPSF);
    float fx = tanhf(SQC * vn) / (SQC * vn);

    // exp_map_zero(rel_trans)
    const float* trow = rtrans + (size_t)r * 512;
    float4 u0 = *(const float4*)(trow + 4 * lane);
    float4 u1 = *(const float4*)(trow + 256 + 4 * lane);
    float tt = dot4(u0, u0) + dot4(u1, u1);
    float rt = dot4(r0, u0) + dot4(r1, u1);
    tt = wred(tt);
    rt = wred(rt);
    float tn = fmaxf(sqrtf(tt), EPSF);
    float fy = tanhf(SQC * tn) / (SQC * tn);

    // mobius_add(x = fx*rot, y = fy*trans)
    float x2 = fx * fx * vv;
    float y2 = fy * fy * tt;
    float xy = fx * fy * rt;
    float ca  = 1.0f + 2.0f * C_C * xy + C_C * y2;
    float cb  = 1.0f - C_C * x2;
    float den = fmaxf(1.0f + 2.0f * C_C * xy + C_C * C_C * x2 * y2, EPSF);
    float inv = 1.0f / den;

    float4 q0, q1;
    q0.x = (ca * fx * r0.x + cb * fy * u0.x) * inv;
    q0.y = (ca * fx * r0.y + cb * fy * u0.y) * inv;
    q0.z = (ca * fx * r0.z + cb * fy * u0.z) * inv;
    q0.w = (ca * fx * r0.w + cb * fy * u0.w) * inv;
    q1.x = (ca * fx * r1.x + cb * fy * u1.x) * inv;
    q1.y = (ca * fx * r1.y + cb * fy * u1.y) * inv;
    q1.z = (ca * fx * r1.z + cb * fy * u1.z) * inv;
    q1.w = (ca * fx * r1.w + cb * fy * u1.w) * inv;

    float qq = dot4(q0, q0) + dot4(q1, q1);
    qq = wred(qq);

    unsigned short* qrow = qb + (size_t)b * 512;
    uint2 h0, h1;
    h0.x = pk2(q0.x, q0.y);  h0.y = pk2(q0.z, q0.w);
    h1.x = pk2(q1.x, q1.y);  h1.y = pk2(q1.z, q1.w);
    *(uint2*)(qrow + 4 * lane)       = h0;
    *(uint2*)(qrow + 256 + 4 * lane) = h1;
    if (lane == 0) {
        q2buf[b] = qq;
        sbbuf[b] = ebias[t0];
    }
}

// ---------------------------------------------------------------------------
// Kernel 2: barrier-free, LDS-free bf16-MFMA scoring.
// One 64-lane wave per 16-entity group (grid = E/16 = 2560 blocks).
//   1. Load the wave's E-block fp32 ONCE (32 x b128, 128B/row/ks fully
//      coalesced), convert to bf16 B-fragments kept in 64 VGPRs, accumulate
//      e2 in-lane (+2 shfl_xor at end).
//   2. Loop qg=0..7: A-fragments read directly from bf16 qb (128KB, L2-hot,
//      same per-lane 16B pattern as the verified R2 kernel), 16 unrolled
//      mfma_f32_16x16x32_bf16 into one 16x16 acc, Mobius epilogue, store.
// No __shared__, no __syncthreads -> waves stream independently; all HBM
// loads issue up-front per wave (deep memory-level parallelism).
// D mapping (verified R2): col = lane&15 = entity, row = (lane>>4)*4+reg = q.
// ---------------------------------------------------------------------------
__global__ __launch_bounds__(64, 4)
void score_direct(const float* __restrict__ ent,
                  const float* __restrict__ ebias,
                  const unsigned short* __restrict__ qb,
                  const float* __restrict__ q2buf,
                  const float* __restrict__ sbbuf,
                  float* __restrict__ out, int E)
{
    const int lane = threadIdx.x;
    const int er   = lane & 15;   // entity row within group / frag row
    const int kg   = lane >> 4;   // k-group 0..3
    const int e0   = blockIdx.x * 16;

    // ---- one-time E load + bf16 conversion + e2
    short8 eb[16];
    float  e2p = 0.0f;
    const float* esrc = ent + (size_t)(e0 + er) * 512 + kg * 8;
#pragma unroll
    for (int ks = 0; ks < 16; ++ks) {
        float4 f0 = *(const float4*)(esrc + ks * 32);
        float4 f1 = *(const float4*)(esrc + ks * 32 + 4);
        e2p += dot4(f0, f0) + dot4(f1, f1);
        uint4 p = { pk2(f0.x, f0.y), pk2(f0.z, f0.w),
                    pk2(f1.x, f1.y), pk2(f1.z, f1.w) };
        eb[ks] = *(short8*)&p;
    }
    // sum the 4 kg-partials of row er (lanes {l, l^16, l^32, l^48})
    e2p += __shfl_xor(e2p, 16, 64);
    e2p += __shfl_xor(e2p, 32, 64);
    const float e2 = e2p;
    const float be = ebias[e0 + er];

    // ---- loop over the 8 query groups
    for (int qg = 0; qg < 8; ++qg) {
        f32x4 acc = (f32x4)0.0f;
        const unsigned short* qp =
            qb + (size_t)(qg * 16 + er) * 512 + kg * 8;
#pragma unroll
        for (int ks = 0; ks < 16; ++ks) {
            short8 a = *(const short8*)(qp + ks * 32);
            acc = __builtin_amdgcn_mfma_f32_16x16x32_bf16(a, eb[ks], acc,
                                                          0, 0, 0);
        }
        // epilogue: q = qg*16 + kg*4 + r, e = e0 + er
        float4 q2v = *(const float4*)(q2buf + qg * 16 + kg * 4);
        float4 sbv = *(const float4*)(sbbuf + qg * 16 + kg * 4);
        const float q2a[4] = { q2v.x, q2v.y, q2v.z, q2v.w };
        const float sba[4] = { sbv.x, sbv.y, sbv.z, sbv.w };
#pragma unroll
        for (int r = 0; r < 4; ++r) {
            const int q   = qg * 16 + kg * 4 + r;
            float q2  = q2a[r];
            float xy  = -acc[r];
            float ca  = 1.0f + 2.0f * C_C * xy + C_C * e2;
            float cb  = 1.0f - C_C * q2;
            float den = fmaxf(1.0f + 2.0f * C_C * xy + C_C * C_C * q2 * e2, EPSF);
            float id2 = 1.0f / (den * den);
            float dist = (ca * ca * q2 + 2.0f * ca * cb * xy + cb * cb * e2) * id2;
            out[(size_t)q * E + e0 + er] = sba[r] + be - dist;
        }
    }
}

extern "C" void kernel_launch(void* const* d_in, const int* in_sizes, int n_in,
                              void* d_out, int out_size, void* d_ws, size_t ws_size,
                              hipStream_t stream) {
    const float* ent    = (const float*)d_in[0];
    // d_in[1] = rel_embedding: unused by the reference
    const float* rrot   = (const float*)d_in[2];
    const float* rtrans = (const float*)d_in[3];
    const float* ebias  = (const float*)d_in[4];
    const int*   trip   = (const int*)d_in[5];
    float* out = (float*)d_out;

    const int B = in_sizes[5] / 3;    // 128
    const int E = in_sizes[0] / 512;  // 40960

    unsigned short* qb = (unsigned short*)d_ws;          // B*512 bf16
    float* q2buf = (float*)(qb + (size_t)B * 512);       // B floats
    float* sbbuf = q2buf + B;                            // B floats

    build_queries<<<B, 64, 0, stream>>>(ent, rrot, rtrans, ebias, trip,
                                        qb, q2buf, sbbuf);
    score_direct<<<E / 16, 64, 0, stream>>>(ent, ebias, qb, q2buf, sbbuf,
                                            out, E);
}

// Round 13
// 170.065 us; speedup vs baseline: 1.0079x; 1.0079x over previous
//
#include <hip/hip_runtime.h>
#include <math.h>

#define C_C   0.01f
#define SQC   0.1f          // sqrt(c)
#define EPSF  1e-15f
#define TCLIP (1.0f - 1e-6f)

typedef short short8 __attribute__((ext_vector_type(8)));
typedef float f32x4  __attribute__((ext_vector_type(4)));

__device__ __forceinline__ float wred(float v) {
#pragma unroll
    for (int off = 32; off > 0; off >>= 1) v += __shfl_xor(v, off, 64);
    return v;
}

__device__ __forceinline__ float dot4(const float4& a, const float4& b) {
    return a.x * b.x + a.y * b.y + a.z * b.z + a.w * b.w;
}

// fp32 -> bf16 round-nearest-even, raw bits
__device__ __forceinline__ unsigned int f2bf(float f) {
    unsigned int u = __float_as_uint(f);
    u += 0x7fffu + ((u >> 16) & 1u);
    return u >> 16;
}
__device__ __forceinline__ unsigned int pk2(float a, float b) {
    return f2bf(a) | (f2bf(b) << 16);
}

// ---------------------------------------------------------------------------
// Kernel 1: build 128 queries; emit bf16 rows + fp32 q2 + subject bias.
// One wave per query.
// ---------------------------------------------------------------------------
__global__ __launch_bounds__(64)
void build_queries(const float* __restrict__ ent,
                   const float* __restrict__ rrot,
                   const float* __restrict__ rtrans,
                   const float* __restrict__ ebias,
                   const int* __restrict__ trip,
                   unsigned short* __restrict__ qb,  // [B][512] bf16 bits
                   float* __restrict__ q2buf,        // [B]
                   float* __restrict__ sbbuf)        // [B]
{
    const int b    = blockIdx.x;
    const int lane = threadIdx.x;
    const int t0   = trip[b * 3 + 0];
    const int r    = trip[b * 3 + 1];

    const float* srow = ent + (size_t)t0 * 512;
    float4 s0 = *(const float4*)(srow + 4 * lane);
    float4 s1 = *(const float4*)(srow + 256 + 4 * lane);

    // log_map_zero
    float ss = dot4(s0, s0) + dot4(s1, s1);
    ss = wred(ss);
    float yn  = fmaxf(sqrtf(ss), EPSF);
    float arg = fminf(SQC * yn, TCLIP);
    float fl  = atanhf(arg) / (SQC * yn);

    // givens rotation on s_tan = fl * s
    const float* arow = rrot + (size_t)r * 256;
    float2 a01 = *(const float2*)(arow + 2 * lane);
    float2 a23 = *(const float2*)(arow + 128 + 2 * lane);
    float c0, n0, c1, n1, c2, n2, c3, n3;
    sincosf(a01.x, &n0, &c0);
    sincosf(a01.y, &n1, &c1);
    sincosf(a23.x, &n2, &c2);
    sincosf(a23.y, &n3, &c3);

    float t0x = s0.x * fl, t0y = s0.y * fl, t0z = s0.z * fl, t0w = s0.w * fl;
    float t1x = s1.x * fl, t1y = s1.y * fl, t1z = s1.z * fl, t1w = s1.w * fl;

    float4 r0, r1;
    r0.x = c0 * t0x - n0 * t0y;  r0.y = n0 * t0x + c0 * t0y;
    r0.z = c1 * t0z - n1 * t0w;  r0.w = n1 * t0z + c1 * t0w;
    r1.x = c2 * t1x - n2 * t1y;  r1.y = n2 * t1x + c2 * t1y;
    r1.z = c3 * t1z - n3 * t1w;  r1.w = n3 * t1z + c3 * t1w;

    // exp_map_zero(rot)
    float vv = dot4(r0, r0) + dot4(r1, r1);
    vv = wred(vv);
    float vn = fmaxf(sqrtf(vv), EPSF);
    float fx = tanhf(SQC * vn) / (SQC * vn);

    // exp_map_zero(rel_trans)
    const float* trow = rtrans + (size_t)r * 512;
    float4 u0 = *(const float4*)(trow + 4 * lane);
    float4 u1 = *(const float4*)(trow + 256 + 4 * lane);
    float tt = dot4(u0, u0) + dot4(u1, u1);
    float rt = dot4(r0, u0) + dot4(r1, u1);
    tt = wred(tt);
    rt = wred(rt);
    float tn = fmaxf(sqrtf(tt), EPSF);
    float fy = tanhf(SQC * tn) / (SQC * tn);

    // mobius_add(x = fx*rot, y = fy*trans)
    float x2 = fx * fx * vv;
    float y2 = fy * fy * tt;
    float xy = fx * fy * rt;
    float ca  = 1.0f + 2.0f * C_C * xy + C_C * y2;
    float cb  = 1.0f - C_C * x2;
    float den = fmaxf(1.0f + 2.0f * C_C * xy + C_C * C_C * x2 * y2, EPSF);
    float inv = 1.0f / den;

    float4 q0, q1;
    q0.x = (ca * fx * r0.x + cb * fy * u0.x) * inv;
    q0.y = (ca * fx * r0.y + cb * fy * u0.y) * inv;
    q0.z = (ca * fx * r0.z + cb * fy * u0.z) * inv;
    q0.w = (ca * fx * r0.w + cb * fy * u0.w) * inv;
    q1.x = (ca * fx * r1.x + cb * fy * u1.x) * inv;
    q1.y = (ca * fx * r1.y + cb * fy * u1.y) * inv;
    q1.z = (ca * fx * r1.z + cb * fy * u1.z) * inv;
    q1.w = (ca * fx * r1.w + cb * fy * u1.w) * inv;

    float qq = dot4(q0, q0) + dot4(q1, q1);
    qq = wred(qq);

    unsigned short* qrow = qb + (size_t)b * 512;
    uint2 h0, h1;
    h0.x = pk2(q0.x, q0.y);  h0.y = pk2(q0.z, q0.w);
    h1.x = pk2(q1.x, q1.y);  h1.y = pk2(q1.z, q1.w);
    *(uint2*)(qrow + 4 * lane)       = h0;
    *(uint2*)(qrow + 256 + 4 * lane) = h1;
    if (lane == 0) {
        q2buf[b] = qq;
        sbbuf[b] = ebias[t0];
    }
}

// ---------------------------------------------------------------------------
// Kernel 2: K-split bf16-MFMA scoring.
// Block = 256 threads = 4 waves, one 16-entity group per block
// (grid = E/16 = 2560 blocks = 10240 waves; ~4 waves/SIMD resident).
// Wave w owns K-quarter [w*128, w*128+128):
//   - E slice loaded with ALL 8 float4 outstanding (deep MLP), converted to
//     4 bf16 fragments (16 VGPRs), e2 partial in-lane (+2 shfl).
//   - qg-loop over 8 query groups: Q fragments direct from L2-hot qb,
//     double-buffered; 4 chained MFMAs per qg (chains 4x shorter than R9).
// End: 2-phase LDS reduce of the 4 K-partials (16KB, [w][qg][lane][4] ->
// b128 conflict-free), 2 barriers total, then Mobius epilogue + store.
// ---------------------------------------------------------------------------
__global__ __launch_bounds__(256, 4)
void score_ksplit(const float* __restrict__ ent,
                  const float* __restrict__ ebias,
                  const unsigned short* __restrict__ qb,
                  const float* __restrict__ q2buf,
                  const float* __restrict__ sbbuf,
                  float* __restrict__ out, int E)
{
    __shared__ float part[2][8][64][4];   // 16 KB
    __shared__ float e2part[4][16];       // 256 B

    const int tid  = threadIdx.x;
    const int lane = tid & 63;
    const int w    = tid >> 6;      // wave id = K-quarter
    const int er   = lane & 15;     // entity row in group (frag col)
    const int kg   = lane >> 4;     // k-subgroup 0..3
    const int e0   = blockIdx.x * 16;
    const int k0   = w * 128 + kg * 8;   // lane's base column

    // ---- E slice: 8 float4 loads, all in flight, then convert + e2
    const float* esrc = ent + (size_t)(e0 + er) * 512 + k0;
    float4 f[8];
#pragma unroll
    for (int i = 0; i < 8; ++i)
        f[i] = *(const float4*)(esrc + (i >> 1) * 32 + (i & 1) * 4);

    short8 eb[4];
    float  e2p = 0.0f;
#pragma unroll
    for (int ks = 0; ks < 4; ++ks) {
        float4 f0 = f[2 * ks], f1 = f[2 * ks + 1];
        e2p += dot4(f0, f0) + dot4(f1, f1);
        uint4 p = { pk2(f0.x, f0.y), pk2(f0.z, f0.w),
                    pk2(f1.x, f1.y), pk2(f1.z, f1.w) };
        eb[ks] = *(short8*)&p;
    }
    e2p += __shfl_xor(e2p, 16, 64);   // sum kg partials of row er
    e2p += __shfl_xor(e2p, 32, 64);
    if (lane < 16) e2part[w][er] = e2p;

    // ---- Q x E: 8 query groups, Q double-buffered from L2-hot qb
    const unsigned short* qbase = qb + (size_t)er * 512 + k0;
    f32x4 acc[8];
#pragma unroll
    for (int qg = 0; qg < 8; ++qg) acc[qg] = (f32x4)0.0f;

    short8 qa[4], qn[4];
#pragma unroll
    for (int ks = 0; ks < 4; ++ks)
        qa[ks] = *(const short8*)(qbase + ks * 32);

#pragma unroll
    for (int qg = 0; qg < 8; ++qg) {
        if (qg < 7) {
#pragma unroll
            for (int ks = 0; ks < 4; ++ks)
                qn[ks] = *(const short8*)(qbase + (size_t)(qg + 1) * 16 * 512
                                          + ks * 32);
        }
#pragma unroll
        for (int ks = 0; ks < 4; ++ks)
            acc[qg] = __builtin_amdgcn_mfma_f32_16x16x32_bf16(
                qa[ks], eb[ks], acc[qg], 0, 0, 0);
#pragma unroll
        for (int ks = 0; ks < 4; ++ks) qa[ks] = qn[ks];
    }

    // ---- 2-phase cross-wave reduce (w0/w1 write; w2/w3 add)
    if (w < 2) {
#pragma unroll
        for (int qg = 0; qg < 8; ++qg)
            *(f32x4*)&part[w][qg][lane][0] = acc[qg];
    }
    __syncthreads();
    if (w >= 2) {
#pragma unroll
        for (int qg = 0; qg < 8; ++qg) {
            f32x4 v = *(f32x4*)&part[w - 2][qg][lane][0];
            v += acc[qg];
            *(f32x4*)&part[w - 2][qg][lane][0] = v;
        }
    }
    __syncthreads();

    // ---- epilogue: thread handles its lane for 2 query groups
    const float e2 = e2part[0][er] + e2part[1][er] +
                     e2part[2][er] + e2part[3][er];
    const float be = ebias[e0 + er];
#pragma unroll
    for (int i = 0; i < 2; ++i) {
        const int qg = w * 2 + i;
        f32x4 d0 = *(f32x4*)&part[0][qg][lane][0];
        f32x4 d1 = *(f32x4*)&part[1][qg][lane][0];
        f32x4 d  = d0 + d1;

        float4 q2v = *(const float4*)(q2buf + qg * 16 + kg * 4);
        float4 sbv = *(const float4*)(sbbuf + qg * 16 + kg * 4);
        const float q2a[4] = { q2v.x, q2v.y, q2v.z, q2v.w };
        const float sba[4] = { sbv.x, sbv.y, sbv.z, sbv.w };
#pragma unroll
        for (int r = 0; r < 4; ++r) {
            const int q  = qg * 16 + kg * 4 + r;
            float q2  = q2a[r];
            float xy  = -d[r];
            float ca  = 1.0f + 2.0f * C_C * xy + C_C * e2;
            float cb  = 1.0f - C_C * q2;
            float den = fmaxf(1.0f + 2.0f * C_C * xy + C_C * C_C * q2 * e2, EPSF);
            float id2 = 1.0f / (den * den);
            float dist = (ca * ca * q2 + 2.0f * ca * cb * xy + cb * cb * e2) * id2;
            out[(size_t)q * E + e0 + er] = sba[r] + be - dist;
        }
    }
}

extern "C" void kernel_launch(void* const* d_in, const int* in_sizes, int n_in,
                              void* d_out, int out_size, void* d_ws, size_t ws_size,
                              hipStream_t stream) {
    const float* ent    = (const float*)d_in[0];
    // d_in[1] = rel_embedding: unused by the reference
    const float* rrot   = (const float*)d_in[2];
    const float* rtrans = (const float*)d_in[3];
    const float* ebias  = (const float*)d_in[4];
    const int*   trip   = (const int*)d_in[5];
    float* out = (float*)d_out;

    const int B = in_sizes[5] / 3;    // 128
    const int E = in_sizes[0] / 512;  // 40960

    unsigned short* qb = (unsigned short*)d_ws;          // B*512 bf16
    float* q2buf = (float*)(qb + (size_t)B * 512);       // B floats
    float* sbbuf = q2buf + B;                            // B floats

    build_queries<<<B, 64, 0, stream>>>(ent, rrot, rtrans, ebias, trip,
                                        qb, q2buf, sbbuf);
    score_ksplit<<<E / 16, 256, 0, stream>>>(ent, ebias, qb, q2buf, sbbuf,
                                             out, E);
}